// Round 1
// baseline (282.827 us; speedup 1.0000x reference)
//
#include <hip/hip_runtime.h>
#include <hip/hip_bf16.h>
#include <stdint.h>

#define D 512
#define N 8192

typedef __attribute__((ext_vector_type(8))) short short8;
typedef __attribute__((ext_vector_type(4))) float f32x4;

static __device__ __forceinline__ unsigned short f2bf(float f) {
  unsigned int u = __builtin_bit_cast(unsigned int, f);
  u += 0x7fffu + ((u >> 16) & 1u);
  return (unsigned short)(u >> 16);
}
static __device__ __forceinline__ float bf2f(unsigned short s) {
  unsigned int u = ((unsigned int)s) << 16;
  return __builtin_bit_cast(float, u);
}

typedef const __attribute__((address_space(1))) unsigned int* gas_ptr;
typedef __attribute__((address_space(3))) unsigned int* las_ptr;
static __device__ __forceinline__ void gload_lds16(const void* g, void* l) {
  __builtin_amdgcn_global_load_lds((gas_ptr)g, (las_ptr)l, 16, 0, 0);
}

// ---------------- cast kernels ----------------
__global__ void cast_z_k(const float* __restrict__ z, unsigned short* __restrict__ zb) {
  int i = blockIdx.x * 256 + threadIdx.x;
  const int n4 = N * D / 4;
  for (; i < n4; i += gridDim.x * 256) {
    float4 v = ((const float4*)z)[i];
    ushort4 o = { f2bf(v.x), f2bf(v.y), f2bf(v.z), f2bf(v.w) };
    ((ushort4*)zb)[i] = o;
  }
}

__global__ void cast_w_k(const float* __restrict__ Wq, const float* __restrict__ Wk,
                         const float* __restrict__ Wv, const float* __restrict__ bq,
                         const float* __restrict__ bk, const float* __restrict__ bv,
                         unsigned short* __restrict__ wb, float* __restrict__ bqkv) {
  const float scale = 0.044194173824159216f;  // 512^-0.5 folded into Wq,bq
  int i = blockIdx.x * 256 + threadIdx.x;
  const int per = D * D / 4;
  if (i < 3 * per) {
    int sec = i / per;
    int w4 = i - sec * per;
    const float* W = sec == 0 ? Wq : (sec == 1 ? Wk : Wv);
    float s = sec == 0 ? scale : 1.0f;
    float4 v = ((const float4*)W)[w4];
    ushort4 o = { f2bf(v.x * s), f2bf(v.y * s), f2bf(v.z * s), f2bf(v.w * s) };
    ((ushort4*)wb)[sec * per + w4] = o;
  }
  if (i < 3 * D) {
    int sec = i >> 9, j = i & (D - 1);
    const float* b = sec == 0 ? bq : (sec == 1 ? bk : bv);
    bqkv[i] = b[j] * (sec == 0 ? scale : 1.0f);
  }
}

// ---------------- NT GEMM, 128x128 tile, BK=64, 4 waves, dbuf 2-phase ----------------
#define BM 128
#define BN 128
#define BK 64

// EPI 0: qkv projection epilogue (bias add, write q/k bf16 row-major, v transposed)
// EPI 1: exp epilogue (write P bf16 + deterministic rowsum partials)
// EPI 2: divide-by-l epilogue (write fp32 out)
template <int EPI>
__global__ __launch_bounds__(256) void gemm_nt(
    const unsigned short* __restrict__ A, int lda,
    const unsigned short* __restrict__ B, int ldb,
    int K, int tiles_n,
    const float* __restrict__ bias,
    unsigned short* __restrict__ o0, unsigned short* __restrict__ o1,
    unsigned short* __restrict__ o2,
    float* __restrict__ lpart, float* __restrict__ outF) {
  __shared__ unsigned short Ash[2][BM * BK];
  __shared__ unsigned short Bsh[2][BN * BK];

  const int t = threadIdx.x;
  const int w = t >> 6, lane = t & 63;
  const int bid = blockIdx.x, nwg = gridDim.x;
  const int cpx = nwg >> 3;                      // grids are %8==0 -> bijective
  const int swz = (bid & 7) * cpx + (bid >> 3);  // XCD-aware swizzle
  const int tm = swz / tiles_n, tn = swz - tm * tiles_n;
  const int row0 = tm * BM, col0 = tn * BN;

  // staging: unit u = i*256 + t ; row = u>>3 ; slot = u&7 ; source col pre-swizzled
  const int srow = t >> 3;
  const int scol = ((t & 7) ^ ((t >> 3) & 7)) * 8;
  const unsigned short* Ab = A + (size_t)(row0 + srow) * lda + scol;
  const unsigned short* Bb = B + (size_t)(col0 + srow) * ldb + scol;
  const int ldsbase = (w * 64) * 8;  // ushort units

  const int l15 = lane & 15, lhi = lane >> 4, lx = lane & 7;
  const int wr = w >> 1, wc = w & 1;
  const int arow = (wr * 64 + l15) * BK;
  const int brow = (wc * 64 + l15) * BK;
  const int ko0 = ((0 + lhi) ^ lx) * 8;  // swizzled 16B-slot for ks=0
  const int ko1 = ((4 + lhi) ^ lx) * 8;  // ks=1

  f32x4 acc[4][4] = {};

  auto stage = [&](int buf, int k0) {
    const unsigned short* a = Ab + k0;
    const unsigned short* b = Bb + k0;
    unsigned short* la = &Ash[buf][ldsbase];
    unsigned short* lb = &Bsh[buf][ldsbase];
#pragma unroll
    for (int i = 0; i < 4; ++i) {
      gload_lds16(a + (size_t)(i * 32) * lda, la + i * 2048);
      gload_lds16(b + (size_t)(i * 32) * ldb, lb + i * 2048);
    }
  };

  const int NT = K / BK;
  stage(0, 0);
  asm volatile("s_waitcnt vmcnt(0)" ::: "memory");
  __syncthreads();
  int cur = 0;
  for (int kt = 0; kt < NT; ++kt) {
    if (kt + 1 < NT) stage(cur ^ 1, (kt + 1) * BK);
    const unsigned short* As = Ash[cur];
    const unsigned short* Bs = Bsh[cur];
#pragma unroll
    for (int ks = 0; ks < 2; ++ks) {
      const int ko = ks ? ko1 : ko0;
      short8 af[4], bg[4];
#pragma unroll
      for (int rf = 0; rf < 4; ++rf)
        af[rf] = *(const short8*)(As + arow + rf * (16 * BK) + ko);
#pragma unroll
      for (int cf = 0; cf < 4; ++cf)
        bg[cf] = *(const short8*)(Bs + brow + cf * (16 * BK) + ko);
#pragma unroll
      for (int rf = 0; rf < 4; ++rf)
#pragma unroll
        for (int cf = 0; cf < 4; ++cf)
          acc[rf][cf] = __builtin_amdgcn_mfma_f32_16x16x32_bf16(af[rf], bg[cf], acc[rf][cf], 0, 0, 0);
    }
    asm volatile("s_waitcnt vmcnt(0)" ::: "memory");
    __syncthreads();
    cur ^= 1;
  }

  const int r0g = row0 + wr * 64;
  const int c0g = col0 + wc * 64;

  if constexpr (EPI == 0) {
    const int sec = col0 >> 9;  // 0=q 1=k 2=v (uniform per workgroup)
#pragma unroll
    for (int cf = 0; cf < 4; ++cf) {
      const int c = c0g + cf * 16 + l15;
      const int cj = c & (D - 1);
      const float bb = bias[c];
#pragma unroll
      for (int rf = 0; rf < 4; ++rf) {
        const int r = r0g + rf * 16 + lhi * 4;
        f32x4 v = acc[rf][cf];
        if (sec == 0) {
#pragma unroll
          for (int g = 0; g < 4; ++g) o0[(size_t)(r + g) * D + cj] = f2bf(v[g] + bb);
        } else if (sec == 1) {
#pragma unroll
          for (int g = 0; g < 4; ++g) o1[(size_t)(r + g) * D + cj] = f2bf(v[g] + bb);
        } else {  // v -> transposed vT[d][m], 4 consecutive m packed into 8B
          ushort4 o = { f2bf(v[0] + bb), f2bf(v[1] + bb), f2bf(v[2] + bb), f2bf(v[3] + bb) };
          *(ushort4*)(o2 + (size_t)cj * N + r) = o;
        }
      }
    }
  }

  if constexpr (EPI == 1) {
    float rs[4][4];
#pragma unroll
    for (int rf = 0; rf < 4; ++rf)
#pragma unroll
      for (int g = 0; g < 4; ++g) rs[rf][g] = 0.f;
#pragma unroll
    for (int cf = 0; cf < 4; ++cf) {
      const int c = c0g + cf * 16 + l15;
#pragma unroll
      for (int rf = 0; rf < 4; ++rf) {
        const int r = r0g + rf * 16 + lhi * 4;
        f32x4 v = acc[rf][cf];
#pragma unroll
        for (int g = 0; g < 4; ++g) {
          unsigned short us = f2bf(__expf(v[g]));
          o0[(size_t)(r + g) * N + c] = us;
          rs[rf][g] += bf2f(us);  // sum the rounded value (numer/denom consistency)
        }
      }
    }
#pragma unroll
    for (int rf = 0; rf < 4; ++rf)
#pragma unroll
      for (int g = 0; g < 4; ++g) {
        float s = rs[rf][g];
        s += __shfl_xor(s, 1);
        s += __shfl_xor(s, 2);
        s += __shfl_xor(s, 4);
        s += __shfl_xor(s, 8);
        rs[rf][g] = s;
      }
    if (l15 == 0) {
      const int slot = tn * 2 + wc;  // deterministic, no atomics
#pragma unroll
      for (int rf = 0; rf < 4; ++rf)
#pragma unroll
        for (int g = 0; g < 4; ++g)
          lpart[(size_t)slot * N + r0g + rf * 16 + lhi * 4 + g] = rs[rf][g];
    }
  }

  if constexpr (EPI == 2) {
    __shared__ float linv[BM];
    {
      const int rr = t >> 1, half = t & 1;
      float s = 0.f;
      for (int i = 0; i < 64; ++i)
        s += lpart[(size_t)(half * 64 + i) * N + row0 + rr];
      s += __shfl_xor(s, 1);
      if (half == 0) linv[rr] = 1.0f / s;
    }
    __syncthreads();
#pragma unroll
    for (int cf = 0; cf < 4; ++cf) {
      const int c = c0g + cf * 16 + l15;
#pragma unroll
      for (int rf = 0; rf < 4; ++rf) {
        const int rl = wr * 64 + rf * 16 + lhi * 4;
        f32x4 v = acc[rf][cf];
#pragma unroll
        for (int g = 0; g < 4; ++g)
          outF[(size_t)(row0 + rl + g) * D + c] = v[g] * linv[rl + g];
      }
    }
  }
}

extern "C" void kernel_launch(void* const* d_in, const int* in_sizes, int n_in,
                              void* d_out, int out_size, void* d_ws, size_t ws_size,
                              hipStream_t stream) {
  const float* z  = (const float*)d_in[0];
  const float* Wq = (const float*)d_in[1];
  const float* bq = (const float*)d_in[2];
  const float* Wk = (const float*)d_in[3];
  const float* bk = (const float*)d_in[4];
  const float* Wv = (const float*)d_in[5];
  const float* bv = (const float*)d_in[6];
  float* out = (float*)d_out;

  char* ws = (char*)d_ws;
  unsigned short* zb = (unsigned short*)(ws + 0);          //  8 MB  z bf16
  unsigned short* qb = (unsigned short*)(ws + 8388608);    //  8 MB  q bf16 (scaled)
  unsigned short* kb = (unsigned short*)(ws + 16777216);   //  8 MB  k bf16
  unsigned short* vT = (unsigned short*)(ws + 25165824);   //  8 MB  v^T bf16 [512][8192]
  unsigned short* wb = (unsigned short*)(ws + 33554432);   //  1.5MB W_qkv bf16 [1536][512]
  float* bqkv       = (float*)(ws + 35127296);             //  6 KB  biases f32
  float* lpart      = (float*)(ws + 35133440);             //  4 MB  rowsum partials [128][8192]
  unsigned short* P = (unsigned short*)(ws + 39327744);    // 128 MB P bf16 [8192][8192]

  cast_z_k<<<dim3(2048), dim3(256), 0, stream>>>(z, zb);
  cast_w_k<<<dim3(768), dim3(256), 0, stream>>>(Wq, Wk, Wv, bq, bk, bv, wb, bqkv);

  // qkv projection: [8192x1536] = zb @ wb^T (+bias), N-tiles 12
  gemm_nt<0><<<dim3(64 * 12), dim3(256), 0, stream>>>(
      zb, D, wb, D, D, 12, bqkv, qb, kb, vT, (float*)nullptr, (float*)nullptr);

  // scores+exp: P = exp(qb @ kb^T), K=512, 64x64 tiles
  gemm_nt<1><<<dim3(64 * 64), dim3(256), 0, stream>>>(
      qb, D, kb, D, D, 64, (const float*)nullptr, P, (unsigned short*)nullptr,
      (unsigned short*)nullptr, lpart, (float*)nullptr);

  // out = (P @ vT^T) / l, K=8192, N-tiles 4
  gemm_nt<2><<<dim3(64 * 4), dim3(256), 0, stream>>>(
      P, N, vT, N, N, 4, (const float*)nullptr, (unsigned short*)nullptr,
      (unsigned short*)nullptr, (unsigned short*)nullptr, lpart, out);
}

// Round 2
// 269.389 us; speedup vs baseline: 1.0499x; 1.0499x over previous
//
#include <hip/hip_runtime.h>
#include <hip/hip_bf16.h>
#include <stdint.h>

#define D 512
#define N 8192

typedef __attribute__((ext_vector_type(8))) short short8;
typedef __attribute__((ext_vector_type(4))) float f32x4;

static __device__ __forceinline__ unsigned short f2bf(float f) {
  unsigned int u = __builtin_bit_cast(unsigned int, f);
  u += 0x7fffu + ((u >> 16) & 1u);
  return (unsigned short)(u >> 16);
}
static __device__ __forceinline__ float bf2f(unsigned short s) {
  unsigned int u = ((unsigned int)s) << 16;
  return __builtin_bit_cast(float, u);
}

typedef const __attribute__((address_space(1))) unsigned int* gas_ptr;
typedef __attribute__((address_space(3))) unsigned int* las_ptr;
static __device__ __forceinline__ void gload_lds16(const void* g, void* l) {
  __builtin_amdgcn_global_load_lds((gas_ptr)g, (las_ptr)l, 16, 0, 0);
}

// ---------------- cast kernels ----------------
__global__ void cast_z_k(const float* __restrict__ z, unsigned short* __restrict__ zb) {
  int i = blockIdx.x * 256 + threadIdx.x;
  const int n4 = N * D / 4;
  for (; i < n4; i += gridDim.x * 256) {
    float4 v = ((const float4*)z)[i];
    ushort4 o = { f2bf(v.x), f2bf(v.y), f2bf(v.z), f2bf(v.w) };
    ((ushort4*)zb)[i] = o;
  }
}

__global__ void cast_w_k(const float* __restrict__ Wq, const float* __restrict__ Wk,
                         const float* __restrict__ Wv, const float* __restrict__ bq,
                         const float* __restrict__ bk, const float* __restrict__ bv,
                         unsigned short* __restrict__ wb, float* __restrict__ bqkv) {
  const float scale = 0.044194173824159216f;  // 512^-0.5 folded into Wq,bq
  int i = blockIdx.x * 256 + threadIdx.x;
  const int per = D * D / 4;
  if (i < 3 * per) {
    int sec = i / per;
    int w4 = i - sec * per;
    const float* W = sec == 0 ? Wq : (sec == 1 ? Wk : Wv);
    float s = sec == 0 ? scale : 1.0f;
    float4 v = ((const float4*)W)[w4];
    ushort4 o = { f2bf(v.x * s), f2bf(v.y * s), f2bf(v.z * s), f2bf(v.w * s) };
    ((ushort4*)wb)[sec * per + w4] = o;
  }
  if (i < 3 * D) {
    int sec = i >> 9, j = i & (D - 1);
    const float* b = sec == 0 ? bq : (sec == 1 ? bk : bv);
    bqkv[i] = b[j] * (sec == 0 ? scale : 1.0f);
  }
}

// ---------------- NT GEMM, 128x128 tile, BK=64, 4 waves, dbuf 2-phase ----------------
#define BM 128
#define BN 128
#define BK 64

// EPI 0: qkv projection epilogue (bias add, write q/k bf16 row-major, v transposed)
// EPI 1: exp epilogue (write P bf16 + deterministic rowsum partials)
// EPI 3: split-K PV epilogue (write bf16 unnormalized partials)
template <int EPI>
__global__ __launch_bounds__(256) void gemm_nt(
    const unsigned short* __restrict__ A, int lda,
    const unsigned short* __restrict__ B, int ldb,
    int K, int tiles_n,
    const float* __restrict__ bias,
    unsigned short* __restrict__ o0, unsigned short* __restrict__ o1,
    unsigned short* __restrict__ o2,
    float* __restrict__ lpart) {
  __shared__ unsigned short Ash[2][BM * BK];
  __shared__ unsigned short Bsh[2][BN * BK];

  const int t = threadIdx.x;
  const int w = t >> 6, lane = t & 63;
  const int bid = blockIdx.x, nwg = gridDim.x;
  const int cpx = nwg >> 3;                      // grids are %8==0 -> bijective
  const int swz = (bid & 7) * cpx + (bid >> 3);  // XCD-aware swizzle
  int tm, tn, kt0 = 0, nkt = K / BK, sidx = 0;
  if constexpr (EPI == 3) {
    sidx = swz >> 8;        // 3 splits of 256 tiles; same-split WGs cluster per XCD
    const int tile = swz & 255;
    tm = tile >> 2;         // tiles_n == 4
    tn = tile & 3;
    kt0 = sidx * 43;        // K-tile chunks 43/43/42
    nkt = (sidx < 2) ? 43 : 42;
  } else {
    tm = swz / tiles_n;
    tn = swz - tm * tiles_n;
  }
  const int row0 = tm * BM, col0 = tn * BN;

  // staging: unit u = i*256 + t ; row = u>>3 ; slot = u&7 ; source col pre-swizzled
  const int srow = t >> 3;
  const int scol = ((t & 7) ^ ((t >> 3) & 7)) * 8;
  const unsigned short* Ab = A + (size_t)(row0 + srow) * lda + scol;
  const unsigned short* Bb = B + (size_t)(col0 + srow) * ldb + scol;
  const int ldsbase = (w * 64) * 8;  // ushort units

  const int l15 = lane & 15, lhi = lane >> 4, lx = lane & 7;
  const int wr = w >> 1, wc = w & 1;
  const int arow = (wr * 64 + l15) * BK;
  const int brow = (wc * 64 + l15) * BK;
  const int ko0 = ((0 + lhi) ^ lx) * 8;  // swizzled 16B-slot for ks=0
  const int ko1 = ((4 + lhi) ^ lx) * 8;  // ks=1

  f32x4 acc[4][4] = {};

  auto stage = [&](int buf, int k0) {
    const unsigned short* a = Ab + k0;
    const unsigned short* b = Bb + k0;
    unsigned short* la = &Ash[buf][ldsbase];
    unsigned short* lb = &Bsh[buf][ldsbase];
#pragma unroll
    for (int i = 0; i < 4; ++i) {
      gload_lds16(a + (size_t)(i * 32) * lda, la + i * 2048);
      gload_lds16(b + (size_t)(i * 32) * ldb, lb + i * 2048);
    }
  };

  stage(0, kt0 * BK);
  asm volatile("s_waitcnt vmcnt(0)" ::: "memory");
  __syncthreads();
  int cur = 0;
  for (int kt = 0; kt < nkt; ++kt) {
    if (kt + 1 < nkt) stage(cur ^ 1, (kt0 + kt + 1) * BK);
    const unsigned short* As = Ash[cur];
    const unsigned short* Bs = Bsh[cur];
#pragma unroll
    for (int ks = 0; ks < 2; ++ks) {
      const int ko = ks ? ko1 : ko0;
      short8 af[4], bg[4];
#pragma unroll
      for (int rf = 0; rf < 4; ++rf)
        af[rf] = *(const short8*)(As + arow + rf * (16 * BK) + ko);
#pragma unroll
      for (int cf = 0; cf < 4; ++cf)
        bg[cf] = *(const short8*)(Bs + brow + cf * (16 * BK) + ko);
#pragma unroll
      for (int rf = 0; rf < 4; ++rf)
#pragma unroll
        for (int cf = 0; cf < 4; ++cf)
          acc[rf][cf] = __builtin_amdgcn_mfma_f32_16x16x32_bf16(af[rf], bg[cf], acc[rf][cf], 0, 0, 0);
    }
    asm volatile("s_waitcnt vmcnt(0)" ::: "memory");
    __syncthreads();
    cur ^= 1;
  }

  const int r0g = row0 + wr * 64;
  const int c0g = col0 + wc * 64;

  if constexpr (EPI == 0) {
    const int sec = col0 >> 9;  // 0=q 1=k 2=v (uniform per workgroup)
#pragma unroll
    for (int cf = 0; cf < 4; ++cf) {
      const int c = c0g + cf * 16 + l15;
      const int cj = c & (D - 1);
      const float bb = bias[c];
#pragma unroll
      for (int rf = 0; rf < 4; ++rf) {
        const int r = r0g + rf * 16 + lhi * 4;
        f32x4 v = acc[rf][cf];
        if (sec == 0) {
#pragma unroll
          for (int g = 0; g < 4; ++g) o0[(size_t)(r + g) * D + cj] = f2bf(v[g] + bb);
        } else if (sec == 1) {
#pragma unroll
          for (int g = 0; g < 4; ++g) o1[(size_t)(r + g) * D + cj] = f2bf(v[g] + bb);
        } else {  // v -> transposed vT[d][m], 4 consecutive m packed into 8B
          ushort4 o = { f2bf(v[0] + bb), f2bf(v[1] + bb), f2bf(v[2] + bb), f2bf(v[3] + bb) };
          *(ushort4*)(o2 + (size_t)cj * N + r) = o;
        }
      }
    }
  }

  if constexpr (EPI == 1) {
    float rs[4][4];
#pragma unroll
    for (int rf = 0; rf < 4; ++rf)
#pragma unroll
      for (int g = 0; g < 4; ++g) rs[rf][g] = 0.f;
#pragma unroll
    for (int cf = 0; cf < 4; ++cf) {
      const int c = c0g + cf * 16 + l15;
#pragma unroll
      for (int rf = 0; rf < 4; ++rf) {
        const int r = r0g + rf * 16 + lhi * 4;
        f32x4 v = acc[rf][cf];
#pragma unroll
        for (int g = 0; g < 4; ++g) {
          unsigned short us = f2bf(__expf(v[g]));
          o0[(size_t)(r + g) * N + c] = us;
          rs[rf][g] += bf2f(us);  // sum the rounded value (numer/denom consistency)
        }
      }
    }
#pragma unroll
    for (int rf = 0; rf < 4; ++rf)
#pragma unroll
      for (int g = 0; g < 4; ++g) {
        float s = rs[rf][g];
        s += __shfl_xor(s, 1);
        s += __shfl_xor(s, 2);
        s += __shfl_xor(s, 4);
        s += __shfl_xor(s, 8);
        rs[rf][g] = s;
      }
    if (l15 == 0) {
      const int slot = tn * 2 + wc;  // deterministic, no atomics
#pragma unroll
      for (int rf = 0; rf < 4; ++rf)
#pragma unroll
        for (int g = 0; g < 4; ++g)
          lpart[(size_t)slot * N + r0g + rf * 16 + lhi * 4 + g] = rs[rf][g];
    }
  }

  if constexpr (EPI == 3) {
    unsigned short* op = o0 + (size_t)sidx * ((size_t)N * D);
#pragma unroll
    for (int cf = 0; cf < 4; ++cf) {
      const int c = c0g + cf * 16 + l15;
#pragma unroll
      for (int rf = 0; rf < 4; ++rf) {
        const int r = r0g + rf * 16 + lhi * 4;
        f32x4 v = acc[rf][cf];
#pragma unroll
        for (int g = 0; g < 4; ++g) op[(size_t)(r + g) * D + c] = f2bf(v[g]);
      }
    }
  }
}

// linv[m] = 1 / sum_slots lpart[slot][m]
__global__ void linv_k(const float* __restrict__ lpart, float* __restrict__ linv) {
  const int m = blockIdx.x * 256 + threadIdx.x;
  float s = 0.f;
  for (int i = 0; i < 128; ++i) s += lpart[(size_t)i * N + m];
  linv[m] = 1.0f / s;
}

// out[m][d] = linv[m] * sum_s Opart[s][m][d]
__global__ void reduce_k(const unsigned short* __restrict__ Opart,
                         const float* __restrict__ linv, float* __restrict__ out) {
  const int i = blockIdx.x * 256 + threadIdx.x;  // over N*D/4
  const int m = i >> 7;                           // 128 float4 per row
  const float li = linv[m];
  const size_t nd = (size_t)N * D;
  ushort4 a = ((const ushort4*)Opart)[i];
  ushort4 b = ((const ushort4*)(Opart + nd))[i];
  ushort4 c = ((const ushort4*)(Opart + 2 * nd))[i];
  float4 o;
  o.x = (bf2f(a.x) + bf2f(b.x) + bf2f(c.x)) * li;
  o.y = (bf2f(a.y) + bf2f(b.y) + bf2f(c.y)) * li;
  o.z = (bf2f(a.z) + bf2f(b.z) + bf2f(c.z)) * li;
  o.w = (bf2f(a.w) + bf2f(b.w) + bf2f(c.w)) * li;
  ((float4*)out)[i] = o;
}

extern "C" void kernel_launch(void* const* d_in, const int* in_sizes, int n_in,
                              void* d_out, int out_size, void* d_ws, size_t ws_size,
                              hipStream_t stream) {
  const float* z  = (const float*)d_in[0];
  const float* Wq = (const float*)d_in[1];
  const float* bq = (const float*)d_in[2];
  const float* Wk = (const float*)d_in[3];
  const float* bk = (const float*)d_in[4];
  const float* Wv = (const float*)d_in[5];
  const float* bv = (const float*)d_in[6];
  float* out = (float*)d_out;

  char* ws = (char*)d_ws;
  unsigned short* zb = (unsigned short*)(ws + 0);          //  8 MB  z bf16
  unsigned short* qb = (unsigned short*)(ws + 8388608);    //  8 MB  q bf16 (scaled)
  unsigned short* kb = (unsigned short*)(ws + 16777216);   //  8 MB  k bf16
  unsigned short* vT = (unsigned short*)(ws + 25165824);   //  8 MB  v^T bf16 [512][8192]
  unsigned short* wb = (unsigned short*)(ws + 33554432);   //  1.5MB W_qkv bf16 [1536][512]
  float* linv       = (float*)(ws + 33554432);             //  32 KB (overlays wb; wb dead after EPI=0)
  float* bqkv       = (float*)(ws + 35127296);             //  6 KB  biases f32
  float* lpart      = (float*)(ws + 35133440);             //  4 MB  rowsum partials [128][8192]
  unsigned short* P = (unsigned short*)(ws + 39327744);    // 128 MB P bf16 [8192][8192]
  // Opart overlays zb+qb+kb (24 MB, dead by the time EPI=3 runs): [3][8192][512] bf16
  unsigned short* Opart = (unsigned short*)(ws + 0);

  cast_z_k<<<dim3(2048), dim3(256), 0, stream>>>(z, zb);
  cast_w_k<<<dim3(768), dim3(256), 0, stream>>>(Wq, Wk, Wv, bq, bk, bv, wb, bqkv);

  // qkv projection: [8192x1536] = zb @ wb^T (+bias), N-tiles 12
  gemm_nt<0><<<dim3(64 * 12), dim3(256), 0, stream>>>(
      zb, D, wb, D, D, 12, bqkv, qb, kb, vT, (float*)nullptr);

  // scores+exp: P = exp(qb @ kb^T), K=512, 64x64 tiles
  gemm_nt<1><<<dim3(64 * 64), dim3(256), 0, stream>>>(
      qb, D, kb, D, D, 64, (const float*)nullptr, P, (unsigned short*)nullptr,
      (unsigned short*)nullptr, lpart);

  // row-sum inverse
  linv_k<<<dim3(32), dim3(256), 0, stream>>>(lpart, linv);

  // split-K PV: Opart[s] = P[:, ks..ke] @ vT[:, ks..ke]^T  (bf16 partials)
  gemm_nt<3><<<dim3(768), dim3(256), 0, stream>>>(
      P, N, vT, N, N, 4, (const float*)nullptr, Opart, (unsigned short*)nullptr,
      (unsigned short*)nullptr, (float*)nullptr);

  // out = linv * sum_s Opart[s]
  reduce_k<<<dim3(4096), dim3(256), 0, stream>>>(Opart, linv, out);
}

// Round 3
// 254.071 us; speedup vs baseline: 1.1132x; 1.0603x over previous
//
#include <hip/hip_runtime.h>
#include <hip/hip_bf16.h>
#include <stdint.h>

#define D 512
#define N 8192

typedef __attribute__((ext_vector_type(8))) short short8;
typedef __attribute__((ext_vector_type(4))) float f32x4;

static __device__ __forceinline__ unsigned short f2bf(float f) {
  unsigned int u = __builtin_bit_cast(unsigned int, f);
  u += 0x7fffu + ((u >> 16) & 1u);
  return (unsigned short)(u >> 16);
}
static __device__ __forceinline__ float bf2f(unsigned short s) {
  unsigned int u = ((unsigned int)s) << 16;
  return __builtin_bit_cast(float, u);
}

typedef const __attribute__((address_space(1))) unsigned int* gas_ptr;
typedef __attribute__((address_space(3))) unsigned int* las_ptr;
static __device__ __forceinline__ void gload_lds16(const void* g, void* l) {
  __builtin_amdgcn_global_load_lds((gas_ptr)g, (las_ptr)l, 16, 0, 0);
}

// ---------------- cast kernels ----------------
__global__ void cast_z_k(const float* __restrict__ z, unsigned short* __restrict__ zb) {
  int i = blockIdx.x * 256 + threadIdx.x;
  const int n4 = N * D / 4;
  for (; i < n4; i += gridDim.x * 256) {
    float4 v = ((const float4*)z)[i];
    ushort4 o = { f2bf(v.x), f2bf(v.y), f2bf(v.z), f2bf(v.w) };
    ((ushort4*)zb)[i] = o;
  }
}

__global__ void cast_w_k(const float* __restrict__ Wq, const float* __restrict__ Wk,
                         const float* __restrict__ Wv, const float* __restrict__ bq,
                         const float* __restrict__ bk, const float* __restrict__ bv,
                         unsigned short* __restrict__ wb, float* __restrict__ bqkv) {
  const float scale = 0.044194173824159216f;  // 512^-0.5 folded into Wq,bq
  int i = blockIdx.x * 256 + threadIdx.x;
  const int per = D * D / 4;
  if (i < 3 * per) {
    int sec = i / per;
    int w4 = i - sec * per;
    const float* W = sec == 0 ? Wq : (sec == 1 ? Wk : Wv);
    float s = sec == 0 ? scale : 1.0f;
    float4 v = ((const float4*)W)[w4];
    ushort4 o = { f2bf(v.x * s), f2bf(v.y * s), f2bf(v.z * s), f2bf(v.w * s) };
    ((ushort4*)wb)[sec * per + w4] = o;
  }
  if (i < 3 * D) {
    int sec = i >> 9, j = i & (D - 1);
    const float* b = sec == 0 ? bq : (sec == 1 ? bk : bv);
    bqkv[i] = b[j] * (sec == 0 ? scale : 1.0f);
  }
}

// ---------------- NT GEMM, 128x128 tile, BK=64, 4 waves, dbuf 2-phase ----------------
#define BM 128
#define BN 128
#define BK 64

// EPI 0: qkv projection epilogue (bias add, write q/k bf16 row-major, v transposed)
// EPI 3: split-K PV epilogue (write bf16 unnormalized partials)
template <int EPI>
__global__ __launch_bounds__(256) void gemm_nt(
    const unsigned short* __restrict__ A, int lda,
    const unsigned short* __restrict__ B, int ldb,
    int K, int tiles_n,
    const float* __restrict__ bias,
    unsigned short* __restrict__ o0, unsigned short* __restrict__ o1,
    unsigned short* __restrict__ o2) {
  __shared__ unsigned short Ash[2][BM * BK];
  __shared__ unsigned short Bsh[2][BN * BK];

  const int t = threadIdx.x;
  const int w = t >> 6, lane = t & 63;
  const int bid = blockIdx.x, nwg = gridDim.x;
  const int cpx = nwg >> 3;                      // grids are %8==0 -> bijective
  const int swz = (bid & 7) * cpx + (bid >> 3);  // XCD-aware swizzle
  int tm, tn, kt0 = 0, nkt = K / BK, sidx = 0;
  if constexpr (EPI == 3) {
    sidx = swz >> 8;        // 3 splits of 256 tiles; same-split WGs cluster per XCD
    const int tile = swz & 255;
    tm = tile >> 2;         // tiles_n == 4
    tn = tile & 3;
    kt0 = sidx * 43;        // K-tile chunks 43/43/42
    nkt = (sidx < 2) ? 43 : 42;
  } else {
    tm = swz / tiles_n;
    tn = swz - tm * tiles_n;
  }
  const int row0 = tm * BM, col0 = tn * BN;

  const int srow = t >> 3;
  const int scol = ((t & 7) ^ ((t >> 3) & 7)) * 8;
  const unsigned short* Ab = A + (size_t)(row0 + srow) * lda + scol;
  const unsigned short* Bb = B + (size_t)(col0 + srow) * ldb + scol;
  const int ldsbase = (w * 64) * 8;  // ushort units

  const int l15 = lane & 15, lhi = lane >> 4, lx = lane & 7;
  const int wr = w >> 1, wc = w & 1;
  const int arow = (wr * 64 + l15) * BK;
  const int brow = (wc * 64 + l15) * BK;
  const int ko0 = ((0 + lhi) ^ lx) * 8;  // swizzled 16B-slot for ks=0
  const int ko1 = ((4 + lhi) ^ lx) * 8;  // ks=1

  f32x4 acc[4][4] = {};

  auto stage = [&](int buf, int k0) {
    const unsigned short* a = Ab + k0;
    const unsigned short* b = Bb + k0;
    unsigned short* la = &Ash[buf][ldsbase];
    unsigned short* lb = &Bsh[buf][ldsbase];
#pragma unroll
    for (int i = 0; i < 4; ++i) {
      gload_lds16(a + (size_t)(i * 32) * lda, la + i * 2048);
      gload_lds16(b + (size_t)(i * 32) * ldb, lb + i * 2048);
    }
  };

  stage(0, kt0 * BK);
  asm volatile("s_waitcnt vmcnt(0)" ::: "memory");
  __syncthreads();
  int cur = 0;
  for (int kt = 0; kt < nkt; ++kt) {
    if (kt + 1 < nkt) stage(cur ^ 1, (kt0 + kt + 1) * BK);
    const unsigned short* As = Ash[cur];
    const unsigned short* Bs = Bsh[cur];
#pragma unroll
    for (int ks = 0; ks < 2; ++ks) {
      const int ko = ks ? ko1 : ko0;
      short8 af[4], bg[4];
#pragma unroll
      for (int rf = 0; rf < 4; ++rf)
        af[rf] = *(const short8*)(As + arow + rf * (16 * BK) + ko);
#pragma unroll
      for (int cf = 0; cf < 4; ++cf)
        bg[cf] = *(const short8*)(Bs + brow + cf * (16 * BK) + ko);
#pragma unroll
      for (int rf = 0; rf < 4; ++rf)
#pragma unroll
        for (int cf = 0; cf < 4; ++cf)
          acc[rf][cf] = __builtin_amdgcn_mfma_f32_16x16x32_bf16(af[rf], bg[cf], acc[rf][cf], 0, 0, 0);
    }
    asm volatile("s_waitcnt vmcnt(0)" ::: "memory");
    __syncthreads();
    cur ^= 1;
  }

  const int r0g = row0 + wr * 64;
  const int c0g = col0 + wc * 64;

  if constexpr (EPI == 0) {
    const int sec = col0 >> 9;  // 0=q 1=k 2=v (uniform per workgroup)
#pragma unroll
    for (int cf = 0; cf < 4; ++cf) {
      const int c = c0g + cf * 16 + l15;
      const int cj = c & (D - 1);
      const float bb = bias[c];
#pragma unroll
      for (int rf = 0; rf < 4; ++rf) {
        const int r = r0g + rf * 16 + lhi * 4;
        f32x4 v = acc[rf][cf];
        if (sec == 0) {
#pragma unroll
          for (int g = 0; g < 4; ++g) o0[(size_t)(r + g) * D + cj] = f2bf(v[g] + bb);
        } else if (sec == 1) {
#pragma unroll
          for (int g = 0; g < 4; ++g) o1[(size_t)(r + g) * D + cj] = f2bf(v[g] + bb);
        } else {  // v -> transposed vT[d][m], 4 consecutive m packed into 8B
          ushort4 o = { f2bf(v[0] + bb), f2bf(v[1] + bb), f2bf(v[2] + bb), f2bf(v[3] + bb) };
          *(ushort4*)(o2 + (size_t)cj * N + r) = o;
        }
      }
    }
  }

  if constexpr (EPI == 3) {
    unsigned short* op = o0 + (size_t)sidx * ((size_t)N * D);
#pragma unroll
    for (int cf = 0; cf < 4; ++cf) {
      const int c = c0g + cf * 16 + l15;
#pragma unroll
      for (int rf = 0; rf < 4; ++rf) {
        const int r = r0g + rf * 16 + lhi * 4;
        f32x4 v = acc[rf][cf];
#pragma unroll
        for (int g = 0; g < 4; ++g) op[(size_t)(r + g) * D + c] = f2bf(v[g]);
      }
    }
  }
}

// ---------------- 256x256 8-phase kernel: P = exp(q k^T) + rowsum partials ----------------
// 512 threads, 8 waves (2M x 4N), BK=64, LDS 128KB (2 K-tile buffers, buf = kt&1).
// Schedule per iter (2 K-tiles): 8 phases; K-tile t's 8 staging loads issued
// front-loaded at phase 4t-4 (just after the buffer's previous occupant retires),
// drained (vmcnt 0) at end of phase 4t-1 -> 3-phase in-flight slack; stage target
// buffer is always the opposite of the phase's read buffer.
__global__ __launch_bounds__(512, 2) void qk_exp_8ph(
    const unsigned short* __restrict__ A,   // qb [N][D]
    const unsigned short* __restrict__ B,   // kb [N][D]
    unsigned short* __restrict__ P,
    float* __restrict__ lpart) {
  __shared__ unsigned short Ash[2][256 * 64];
  __shared__ unsigned short Bsh[2][256 * 64];

  const int t = threadIdx.x;
  const int w = t >> 6, lane = t & 63;
  const int bid = blockIdx.x;
  const int swz = (bid & 7) * 128 + (bid >> 3);  // 1024 WGs, bijective
  const int tm = swz >> 5, tn = swz & 31;
  const int row0 = tm * 256, col0 = tn * 256;

  const int wr = w >> 2, wc = w & 3;
  const int l15 = lane & 15, lhi = lane >> 4, lx = lane & 7;

  // staging: thread t, region r64 = load index (0..3): rows r64*64 + (t>>3),
  // source col pre-swizzled so LDS stays linear (slot' = slot ^ (row&7))
  const int sr = t >> 3;
  const int ss = ((t & 7) ^ (sr & 7)) * 8;
  const unsigned short* Ab = A + (size_t)(row0 + sr) * D + ss;
  const unsigned short* Bb = B + (size_t)(col0 + sr) * D + ss;
  const int ldst = t * 8;  // ushort offset

  // fragment-read bases: A row_local = wr*128 + mh*64 + fm*16 + l15
  //                      B row_local = wc*64  + nh*32 + fn*16 + l15
  // phys 16B-slot = (ks*4 + lhi) ^ (row_local&7) = (ks*4+lhi) ^ (l15&7)
  const int aRowB = (wr * 128 + l15) * 64;
  const int bRowB = (wc * 64 + l15) * 64;
  const int sl0 = ((0 + lhi) ^ lx) * 8;
  const int sl1 = ((4 + lhi) ^ lx) * 8;

  f32x4 acc[8][4] = {};
  short8 af[4][2], bf[2][2];

#define STAGE8(buf, kt)                                                     \
  do {                                                                      \
    const unsigned short* a_ = Ab + (kt) * 64;                              \
    const unsigned short* b_ = Bb + (kt) * 64;                              \
    unsigned short* la_ = &Ash[buf][0];                                     \
    unsigned short* lb_ = &Bsh[buf][0];                                     \
    gload_lds16(a_, la_ + ldst);                                            \
    gload_lds16(a_ + (size_t)64 * D, la_ + 4096 + ldst);                    \
    gload_lds16(a_ + (size_t)128 * D, la_ + 8192 + ldst);                   \
    gload_lds16(a_ + (size_t)192 * D, la_ + 12288 + ldst);                  \
    gload_lds16(b_, lb_ + ldst);                                            \
    gload_lds16(b_ + (size_t)64 * D, lb_ + 4096 + ldst);                    \
    gload_lds16(b_ + (size_t)128 * D, lb_ + 8192 + ldst);                   \
    gload_lds16(b_ + (size_t)192 * D, lb_ + 12288 + ldst);                  \
  } while (0)

#define RDA(kk, mh)                                                          \
  do {                                                                       \
    _Pragma("unroll") for (int fm = 0; fm < 4; ++fm) {                       \
      const unsigned short* p_ = &Ash[kk][aRowB + (mh) * 4096 + fm * 1024];  \
      af[fm][0] = *(const short8*)(p_ + sl0);                                \
      af[fm][1] = *(const short8*)(p_ + sl1);                                \
    }                                                                        \
  } while (0)

#define RDB(kk, nh)                                                          \
  do {                                                                       \
    _Pragma("unroll") for (int fn = 0; fn < 2; ++fn) {                       \
      const unsigned short* p_ = &Bsh[kk][bRowB + (nh) * 2048 + fn * 1024];  \
      bf[fn][0] = *(const short8*)(p_ + sl0);                                \
      bf[fn][1] = *(const short8*)(p_ + sl1);                                \
    }                                                                        \
  } while (0)

#define MMA(mh, nh)                                                          \
  do {                                                                       \
    __builtin_amdgcn_s_setprio(1);                                           \
    _Pragma("unroll") for (int ks = 0; ks < 2; ++ks)                         \
      _Pragma("unroll") for (int fm = 0; fm < 4; ++fm)                       \
        _Pragma("unroll") for (int fn = 0; fn < 2; ++fn)                     \
          acc[(mh) * 4 + fm][(nh) * 2 + fn] =                                \
              __builtin_amdgcn_mfma_f32_16x16x32_bf16(                       \
                  af[fm][ks], bf[fn][ks], acc[(mh) * 4 + fm][(nh) * 2 + fn], \
                  0, 0, 0);                                                  \
    __builtin_amdgcn_s_setprio(0);                                           \
  } while (0)

#define BARLG()                                         \
  do {                                                  \
    __builtin_amdgcn_s_barrier();                       \
    asm volatile("s_waitcnt lgkmcnt(0)" ::: "memory");  \
    __builtin_amdgcn_sched_barrier(0);                  \
  } while (0)

#define VMDRAIN() asm volatile("s_waitcnt vmcnt(0)" ::: "memory")
#define POSTBAR() __builtin_amdgcn_s_barrier()

  // prologue: K-tile 0 -> buf0
  STAGE8(0, 0);
  VMDRAIN();
  __builtin_amdgcn_s_barrier();

  const int NI = (D / 64) / 2;  // 4 iterations, 2 K-tiles each
  for (int i = 0; i < NI; ++i) {
    // ---- K-tile 2i (buf0): snake (0,0)->(0,1)->(1,1)->(1,0) ----
    RDA(0, 0); RDB(0, 0);
    STAGE8(1, 2 * i + 1);            // stage kt 2i+1 -> buf1 (free since end of prev iter)
    BARLG(); MMA(0, 0); POSTBAR();

    RDB(0, 1);
    BARLG(); MMA(0, 1); POSTBAR();

    RDA(0, 1);
    BARLG(); MMA(1, 1); POSTBAR();

    RDB(0, 0);
    VMDRAIN();                       // kt 2i+1 landed (3-phase slack)
    BARLG(); MMA(1, 0); POSTBAR();

    // ---- K-tile 2i+1 (buf1) ----
    RDA(1, 0); RDB(1, 0);
    if (i + 1 < NI) STAGE8(0, 2 * i + 2);  // buf0 free since previous POSTBAR
    BARLG(); MMA(0, 0); POSTBAR();

    RDB(1, 1);
    BARLG(); MMA(0, 1); POSTBAR();

    RDA(1, 1);
    BARLG(); MMA(1, 1); POSTBAR();

    RDB(1, 0);
    if (i + 1 < NI) VMDRAIN();       // kt 2i+2 landed
    BARLG(); MMA(1, 0); POSTBAR();
  }

  // ---- epilogue: exp -> bf16 P + deterministic rowsum partials ----
#pragma unroll
  for (int fm = 0; fm < 8; ++fm) {
    const int r = row0 + wr * 128 + fm * 16 + lhi * 4;
    float rs[4] = {0.f, 0.f, 0.f, 0.f};
#pragma unroll
    for (int fn = 0; fn < 4; ++fn) {
      const int c = col0 + wc * 64 + fn * 16 + l15;
      f32x4 v = acc[fm][fn];
#pragma unroll
      for (int g = 0; g < 4; ++g) {
        unsigned short us = f2bf(__expf(v[g]));
        P[(size_t)(r + g) * N + c] = us;
        rs[g] += bf2f(us);  // sum the rounded value (numer/denom consistency)
      }
    }
#pragma unroll
    for (int g = 0; g < 4; ++g) {
      float s = rs[g];
      s += __shfl_xor(s, 1);
      s += __shfl_xor(s, 2);
      s += __shfl_xor(s, 4);
      s += __shfl_xor(s, 8);
      if (l15 == 0) lpart[(size_t)(tn * 4 + wc) * N + r + g] = s;
    }
  }
#undef STAGE8
#undef RDA
#undef RDB
#undef MMA
#undef BARLG
#undef VMDRAIN
#undef POSTBAR
}

// linv[m] = 1 / sum_slots lpart[slot][m]
__global__ void linv_k(const float* __restrict__ lpart, float* __restrict__ linv) {
  const int m = blockIdx.x * 256 + threadIdx.x;
  float s = 0.f;
  for (int i = 0; i < 128; ++i) s += lpart[(size_t)i * N + m];
  linv[m] = 1.0f / s;
}

// out[m][d] = linv[m] * sum_s Opart[s][m][d]
__global__ void reduce_k(const unsigned short* __restrict__ Opart,
                         const float* __restrict__ linv, float* __restrict__ out) {
  const int i = blockIdx.x * 256 + threadIdx.x;  // over N*D/4
  const int m = i >> 7;                           // 128 float4 per row
  const float li = linv[m];
  const size_t nd = (size_t)N * D;
  ushort4 a = ((const ushort4*)Opart)[i];
  ushort4 b = ((const ushort4*)(Opart + nd))[i];
  ushort4 c = ((const ushort4*)(Opart + 2 * nd))[i];
  float4 o;
  o.x = (bf2f(a.x) + bf2f(b.x) + bf2f(c.x)) * li;
  o.y = (bf2f(a.y) + bf2f(b.y) + bf2f(c.y)) * li;
  o.z = (bf2f(a.z) + bf2f(b.z) + bf2f(c.z)) * li;
  o.w = (bf2f(a.w) + bf2f(b.w) + bf2f(c.w)) * li;
  ((float4*)out)[i] = o;
}

extern "C" void kernel_launch(void* const* d_in, const int* in_sizes, int n_in,
                              void* d_out, int out_size, void* d_ws, size_t ws_size,
                              hipStream_t stream) {
  const float* z  = (const float*)d_in[0];
  const float* Wq = (const float*)d_in[1];
  const float* bq = (const float*)d_in[2];
  const float* Wk = (const float*)d_in[3];
  const float* bk = (const float*)d_in[4];
  const float* Wv = (const float*)d_in[5];
  const float* bv = (const float*)d_in[6];
  float* out = (float*)d_out;

  char* ws = (char*)d_ws;
  unsigned short* zb = (unsigned short*)(ws + 0);          //  8 MB  z bf16
  unsigned short* qb = (unsigned short*)(ws + 8388608);    //  8 MB  q bf16 (scaled)
  unsigned short* kb = (unsigned short*)(ws + 16777216);   //  8 MB  k bf16
  unsigned short* vT = (unsigned short*)(ws + 25165824);   //  8 MB  v^T bf16 [512][8192]
  unsigned short* wb = (unsigned short*)(ws + 33554432);   //  1.5MB W_qkv bf16 [1536][512]
  float* linv       = (float*)(ws + 33554432);             //  32 KB (overlays wb; wb dead after EPI=0)
  float* bqkv       = (float*)(ws + 35127296);             //  6 KB  biases f32
  float* lpart      = (float*)(ws + 35133440);             //  4 MB  rowsum partials [128][8192]
  unsigned short* P = (unsigned short*)(ws + 39327744);    // 128 MB P bf16 [8192][8192]
  // Opart overlays zb+qb+kb (24 MB, dead by the time EPI=3 runs): [3][8192][512] bf16
  unsigned short* Opart = (unsigned short*)(ws + 0);

  cast_z_k<<<dim3(2048), dim3(256), 0, stream>>>(z, zb);
  cast_w_k<<<dim3(768), dim3(256), 0, stream>>>(Wq, Wk, Wv, bq, bk, bv, wb, bqkv);

  // qkv projection: [8192x1536] = zb @ wb^T (+bias), N-tiles 12
  gemm_nt<0><<<dim3(64 * 12), dim3(256), 0, stream>>>(
      zb, D, wb, D, D, 12, bqkv, qb, kb, vT);

  // scores+exp: P = exp(qb @ kb^T), 256x256 8-phase engine, 32x32 tiles
  qk_exp_8ph<<<dim3(1024), dim3(512), 0, stream>>>(qb, kb, P, lpart);

  // row-sum inverse
  linv_k<<<dim3(32), dim3(256), 0, stream>>>(lpart, linv);

  // split-K PV: Opart[s] = P[:, ks..ke] @ vT[:, ks..ke]^T  (bf16 partials)
  gemm_nt<3><<<dim3(768), dim3(256), 0, stream>>>(
      P, N, vT, N, N, 4, (const float*)nullptr, Opart, (unsigned short*)nullptr,
      (unsigned short*)nullptr);

  // out = linv * sum_s Opart[s]
  reduce_k<<<dim3(4096), dim3(256), 0, stream>>>(Opart, linv, out);
}